// Round 9
// baseline (1236.064 us; speedup 1.0000x reference)
//
#include <hip/hip_runtime.h>
#include <hip/hip_fp16.h>

#define RES 512
#define NF 32
#define NBINS 4096

typedef float v2f __attribute__((ext_vector_type(2)));
typedef float v4f __attribute__((ext_vector_type(4)));

static __device__ __forceinline__ float h2f(float v) {
    return __half2float(__float2half(v));
}
static __device__ __forceinline__ v2f mkv2(float a, float b) { v2f r; r.x = a; r.y = b; return r; }
static __device__ __forceinline__ v4f mkv4(float a, float b, float c, float d) {
    v4f r; r.x = a; r.y = b; r.z = c; r.w = d; return r;
}

template <int L>
static __device__ __forceinline__ float qb(float v) {
    return __int_as_float(__builtin_amdgcn_mov_dpp(
        __float_as_int(v), (L | (L << 2) | (L << 4) | (L << 6)), 0xf, 0xf, true));
}
static __device__ __forceinline__ float qsum(float v) {
    v += __int_as_float(__builtin_amdgcn_mov_dpp(__float_as_int(v), 0xB1, 0xf, 0xf, true)); // [1,0,3,2]
    v += __int_as_float(__builtin_amdgcn_mov_dpp(__float_as_int(v), 0x4E, 0xf, 0xf, true)); // [2,3,0,1]
    return v;
}

#define GET(v, c) ((c) == 0 ? (v).x : ((c) == 1 ? (v).y : ((c) == 2 ? (v).z : (v).w)))

// ---- Morton 12-bit cell key (4 bits per axis; cells are 32^3 grid units) ----
static __device__ __forceinline__ unsigned part1by2(unsigned v) {
    v &= 0x3FF;
    v = (v | v << 16) & 0x30000FF;
    v = (v | v << 8)  & 0x300F00F;
    v = (v | v << 4)  & 0x30C30C3;
    v = (v | v << 2)  & 0x9249249;
    return v;
}
static __device__ __forceinline__ unsigned cellkey(const float* __restrict__ x, int p) {
    unsigned c[3];
#pragma unroll
    for (int a = 0; a < 3; ++a) {
        float xt = (x[3 * p + a] + 1.0f) * 0.5f;
        float pos = xt * 511.0f;
        int q = (int)floorf(pos);
        q = q < 0 ? 0 : (q > 511 ? 511 : q);
        c[a] = (unsigned)q >> 5;  // 0..15
    }
    return (part1by2(c[0]) << 2) | (part1by2(c[1]) << 1) | part1by2(c[2]);
}

// ---------------- sort passes (spatial binning for gather locality) ----------------
__global__ void zero_hist(unsigned* __restrict__ h) {
    h[blockIdx.x * 256 + threadIdx.x] = 0u;
}
__global__ void hist_pass(const float* __restrict__ x, unsigned* __restrict__ hist, int N) {
    for (int p = blockIdx.x * 256 + threadIdx.x; p < N; p += gridDim.x * 256)
        atomicAdd(&hist[cellkey(x, p)], 1u);
}
__global__ void scan_pass(const unsigned* __restrict__ hist, unsigned* __restrict__ cursor) {
    __shared__ unsigned part[257];
    const int t = threadIdx.x;
    unsigned s = 0;
#pragma unroll
    for (int i = 0; i < NBINS / 256; ++i) s += hist[t * (NBINS / 256) + i];
    part[t + 1] = s;
    if (t == 0) part[0] = 0;
    __syncthreads();
    if (t == 0)
        for (int i = 1; i <= 256; ++i) part[i] += part[i - 1];
    __syncthreads();
    unsigned run = part[t];
    for (int i = 0; i < NBINS / 256; ++i) {
        const int b = t * (NBINS / 256) + i;
        const unsigned c = hist[b];
        cursor[b] = run;
        run += c;
    }
}
__global__ void scatter_pass(const float* __restrict__ x, unsigned* __restrict__ cursor,
                             unsigned* __restrict__ order, int N) {
    for (int p = blockIdx.x * 256 + threadIdx.x; p < N; p += gridDim.x * 256) {
        const unsigned idx = atomicAdd(&cursor[cellkey(x, p)], 1u);
        order[idx] = (unsigned)p;
    }
}

// FOUR LANES (one hardware quad) PER POINT; lane q owns cols {4q..4q+3} and
// {16+4q..16+4q+3}. Round-8 passing structure (VGPR=64, conflicts=0) with one
// addition: points are processed in MORTON-SORTED spatial order (order[]).
// Rationale: 5 structural variants all pinned at ~600us with FETCH_SIZE
// 1.75GB >> 100MB planes — random point order defeats L2/L3 reuse (unique
// texel demand 1536B/pt; sorted 64^3 regions need only ~386B/pt with a 1.6MB
// L2-resident panel set). Outputs still write to the ORIGINAL p slots, so
// results are bit-identical and order-independent.
__global__ __launch_bounds__(256) void stylesdf_fused(
    const float* __restrict__ x,
    const float* __restrict__ planes,
    const float* __restrict__ W1,
    const float* __restrict__ b1,
    const float* __restrict__ W2,
    const float* __restrict__ b2,
    const unsigned* __restrict__ order,
    float* __restrict__ out, int N)
{
#pragma clang fp contract(off)
    __shared__ __align__(16) float sW1[NF * NF];   // fp16-valued W1*s, [i][j]
    __shared__ __align__(16) float sW1T[NF * NF];  // transposed [j][i]
    __shared__ __align__(16) float sW2[NF * 4];    // fp16-valued W2*s
    __shared__ __align__(16) float sB1[NF];
    __shared__ __align__(16) float sB2[4];
    __shared__ __align__(16) float sW2c0[NF];

    const float S16 = h2f(0.17677669529663687f);  // fp16(1/sqrt(32))
    const float LREL = h2f(0.2f);                 // fp16(0.2)

    const int tid = threadIdx.x;
    for (int idx = tid; idx < NF * NF; idx += 256) {
        sW1[idx] = h2f(h2f(W1[idx]) * S16);  // fp16 multiply semantics
        // transposed GLOBAL read (W1 is 4KB, L1-cached), LINEAR LDS write:
        // zero bank conflicts (LDS scatter-write was 3.25e7 conflict cycles).
        sW1T[idx] = h2f(h2f(W1[(idx & 31) * NF + (idx >> 5)]) * S16);
    }
    if (tid < NF * 4) sW2[tid] = h2f(h2f(W2[tid]) * S16);
    if (tid < NF) { sB1[tid] = h2f(b1[tid]); sW2c0[tid] = h2f(h2f(W2[tid * 4]) * S16); }
    if (tid < 4) sB2[tid] = h2f(b2[tid]);
    __syncthreads();

    const int gt = blockIdx.x * 256 + tid;
    const int gq = gt >> 2;           // sorted quad slot
    if (gq >= N) return;
    const int p = order ? (int)order[gq] : gq;   // ORIGINAL point index
    const int q = gt & 3;             // feature-quarter owned by this lane
    const int fq = q << 2;            // 4q: first col of this lane's low slice

    // ---- per-axis interp coordinates (identical ops to passing kernel) ----
    float fr0, fr1, fr2;
    int a0lo, a0hi, a1lo, a1hi, a2lo, a2hi;
#define AXIS(c, FR, LO, HI)                                 \
    {                                                       \
        float xt = (x[3 * p + (c)] + 1.0f) * 0.5f;          \
        float pos = xt * 511.0f;                            \
        float pf = floorf(pos);                             \
        FR = pos - pf;                                      \
        int qq = (int)pf;                                   \
        qq = qq < 0 ? 0 : (qq > 511 ? 511 : qq);            \
        LO = qq;                                            \
        HI = (qq + 1 > 511) ? 511 : qq + 1;                 \
    }
    AXIS(0, fr0, a0lo, a0hi)
    AXIS(1, fr1, a1lo, a1hi)
    AXIS(2, fr2, a2lo, a2hi)
#undef AXIS

    // element offsets of the 12 corner rows (plane bases stay in SGPRs)
    const int oA00 = (a0lo * RES + a1lo) << 5, oA01 = (a0lo * RES + a1hi) << 5;
    const int oA10 = (a0hi * RES + a1lo) << 5, oA11 = (a0hi * RES + a1hi) << 5;
    const int oB00 = (a0lo * RES + a2lo) << 5, oB01 = (a0lo * RES + a2hi) << 5;
    const int oB10 = (a0hi * RES + a2lo) << 5, oB11 = (a0hi * RES + a2hi) << 5;
    const int oC00 = (a1lo * RES + a2lo) << 5, oC01 = (a1lo * RES + a2hi) << 5;
    const int oC10 = (a1hi * RES + a2lo) << 5, oC11 = (a1hi * RES + a2hi) << 5;
    const float* pl0 = planes;
    const float* pl1 = planes + RES * RES * NF;
    const float* pl2 = planes + 2 * (RES * RES * NF);

#define LD4(b, off) (*(const float4*)((b) + (off)))

    const float ifa01 = 1.0f - fr0, ifb01 = 1.0f - fr1;  // plane0 axes (0,1)
    const float ifa02 = 1.0f - fr0, ifb02 = 1.0f - fr2;  // plane1 axes (0,2)
    const float ifa12 = 1.0f - fr1, ifb12 = 1.0f - fr2;  // plane2 axes (1,2)

    // ============ gather: this lane's 8 features, t = c + 4*kk ============
    float hl[8];                      // fp16-rounded h values (y-matvec input)
    float d0l[8], d1l[8], d2l[8];     // fp32 per-axis derivative values
    v4f* ho = (v4f*)(out + (size_t)N + (size_t)p * NF);

#pragma unroll
    for (int kk = 0; kk < 2; ++kk) {
        const int fo = fq + 16 * kk;  // quad covers one 64B segment per row
        const float4 vA00 = LD4(pl0, oA00 + fo), vA01 = LD4(pl0, oA01 + fo);
        const float4 vA10 = LD4(pl0, oA10 + fo), vA11 = LD4(pl0, oA11 + fo);
        const float4 vB00 = LD4(pl1, oB00 + fo), vB01 = LD4(pl1, oB01 + fo);
        const float4 vB10 = LD4(pl1, oB10 + fo), vB11 = LD4(pl1, oB11 + fo);
        const float4 vC00 = LD4(pl2, oC00 + fo), vC01 = LD4(pl2, oC01 + fo);
        const float4 vC10 = LD4(pl2, oC10 + fo), vC11 = LD4(pl2, oC11 + fo);
        float hc[4];
#pragma unroll
        for (int c = 0; c < 4; ++c) {
            const int f = 4 * kk + c;
            {  // plane 0, axes (0,1): bitwise h order: h = (h + t4) + t8
                const float a00 = GET(vA00, c), a01 = GET(vA01, c);
                const float a10 = GET(vA10, c), a11 = GET(vA11, c);
                const float t4 = (a00 * ifb01 + a01 * fr1) * ifa01;
                const float t8 = (a10 * ifb01 + a11 * fr1) * fr0;
                hc[c] = t4 + t8;  // (0+t4)+t8 == t4+t8 value-exact
                d0l[f] = (a10 - a00) * ifb01 + (a11 - a01) * fr1;
                d1l[f] = (a01 - a00) * ifa01 + (a11 - a10) * fr0;
            }
            {  // plane 1, axes (0,2)
                const float a00 = GET(vB00, c), a01 = GET(vB01, c);
                const float a10 = GET(vB10, c), a11 = GET(vB11, c);
                const float t4 = (a00 * ifb02 + a01 * fr2) * ifa02;
                const float t8 = (a10 * ifb02 + a11 * fr2) * fr0;
                hc[c] = (hc[c] + t4) + t8;
                d0l[f] += (a10 - a00) * ifb02 + (a11 - a01) * fr2;
                d2l[f] = (a01 - a00) * ifa02 + (a11 - a10) * fr0;
            }
            {  // plane 2, axes (1,2)
                const float a00 = GET(vC00, c), a01 = GET(vC01, c);
                const float a10 = GET(vC10, c), a11 = GET(vC11, c);
                const float t4 = (a00 * ifb12 + a01 * fr2) * ifa12;
                const float t8 = (a10 * ifb12 + a11 * fr2) * fr1;
                hc[c] = (hc[c] + t4) + t8;
                d1l[f] += (a10 - a00) * ifb12 + (a11 - a01) * fr2;
                d2l[f] += (a01 - a00) * ifa12 + (a11 - a10) * fr1;
            }
            hl[f] = h2f(hc[c]);  // h16
        }
        // fp32 h store, np order; quad writes two full 64B sectors per point.
        __builtin_nontemporal_store(mkv4(hc[0], hc[1], hc[2], hc[3]),
                                    &ho[q + 4 * kk]);
    }

    // ====== y for this lane's 8 cols — EXACT i-sequential order, packed ======
    v2f y2[4];
    y2[0] = mkv2(0.f, 0.f); y2[1] = mkv2(0.f, 0.f);
    y2[2] = mkv2(0.f, 0.f); y2[3] = mkv2(0.f, 0.f);

#define YSTEP(half, ow, e)                                                     \
    {                                                                          \
        const int i = 16 * (half) + 4 * (ow) + (e);                            \
        const float hi = qb<(ow)>(hl[(e) + 4 * (half)]);                       \
        const v2f hv = mkv2(hi, hi);                                           \
        const float4 wA = *(const float4*)(sW1 + i * NF + fq);                 \
        const float4 wB = *(const float4*)(sW1 + i * NF + fq + 16);            \
        y2[0] = y2[0] + hv * mkv2(wA.x, wA.y);  /* round mul, round add */     \
        y2[1] = y2[1] + hv * mkv2(wA.z, wA.w);                                 \
        y2[2] = y2[2] + hv * mkv2(wB.x, wB.y);                                 \
        y2[3] = y2[3] + hv * mkv2(wB.z, wB.w);                                 \
    }
#define Y4(half, ow) YSTEP(half, ow, 0) YSTEP(half, ow, 1) YSTEP(half, ow, 2) YSTEP(half, ow, 3)
#define Y16(half) Y4(half, 0) Y4(half, 1) Y4(half, 2) Y4(half, 3)
    Y16(0) Y16(1)
#undef Y16
#undef Y4
#undef YSTEP

    // ====== activations, layer-2 partials, m for this lane's cols ======
    float o0 = 0.f, o1 = 0.f, o2 = 0.f, o3 = 0.f;
    float ml[8];
#pragma unroll
    for (int t = 0; t < 8; ++t) {
        const int j = fq + (t & 3) + 16 * (t >> 2);
        const float yt = (t & 1) ? y2[t >> 1].y : y2[t >> 1].x;
        const float yd = h2f(yt);               // fp16 dot result
        const float y16 = h2f(yd + sB1[j]);     // fp16 bias add
        const bool nn = y16 >= 0.0f;
        const float zj = nn ? y16 : h2f(LREL * y16);  // fp16 leaky value
        const float4 w2 = ((const float4*)sW2)[j];
        o0 = o0 + zj * w2.x;  // per-lane fp32 partial (pre-round, value-level)
        o1 = o1 + zj * w2.y;
        o2 = o2 + zj * w2.z;
        o3 = o3 + zj * w2.w;
        ml[t] = (nn ? 1.0f : LREL) * sW2c0[j];
    }

    // ====== g for this lane's 8 rows — j ascending, packed fma ======
    v2f g2[4];
    g2[0] = mkv2(0.f, 0.f); g2[1] = mkv2(0.f, 0.f);
    g2[2] = mkv2(0.f, 0.f); g2[3] = mkv2(0.f, 0.f);

#define GSTEP(half, ow, e)                                                     \
    {                                                                          \
        const int j = 16 * (half) + 4 * (ow) + (e);                            \
        const float mj = qb<(ow)>(ml[(e) + 4 * (half)]);                       \
        const v2f mv = mkv2(mj, mj);                                           \
        const float4 wA = *(const float4*)(sW1T + j * NF + fq);                \
        const float4 wB = *(const float4*)(sW1T + j * NF + fq + 16);           \
        g2[0] = __builtin_elementwise_fma(mv, mkv2(wA.x, wA.y), g2[0]);        \
        g2[1] = __builtin_elementwise_fma(mv, mkv2(wA.z, wA.w), g2[1]);        \
        g2[2] = __builtin_elementwise_fma(mv, mkv2(wB.x, wB.y), g2[2]);        \
        g2[3] = __builtin_elementwise_fma(mv, mkv2(wB.z, wB.w), g2[3]);        \
    }
#define G4(half, ow) GSTEP(half, ow, 0) GSTEP(half, ow, 1) GSTEP(half, ow, 2) GSTEP(half, ow, 3)
#define G16(half) G4(half, 0) G4(half, 1) G4(half, 2) G4(half, 3)
    G16(0) G16(1)
#undef G16
#undef G4
#undef GSTEP

    // ====== nabla partials over this lane's rows, then quad tree add ======
    float n0 = 0.f, n1 = 0.f, n2 = 0.f;
#pragma unroll
    for (int t = 0; t < 8; ++t) {
        const float gt_ = (t & 1) ? g2[t >> 1].y : g2[t >> 1].x;
        n0 = fmaf(gt_, d0l[t], n0);
        n1 = fmaf(gt_, d1l[t], n1);
        n2 = fmaf(gt_, d2l[t], n2);
    }

    o0 = qsum(o0); o1 = qsum(o1); o2 = qsum(o2); o3 = qsum(o3);
    n0 = qsum(n0); n1 = qsum(n1); n2 = qsum(n2);

    // fp16 rounding of layer-2 output + bias
    o0 = h2f(h2f(o0) + sB2[0]);
    o1 = h2f(h2f(o1) + sB2[1]);
    o2 = h2f(h2f(o2) + sB2[2]);
    o3 = h2f(h2f(o3) + sB2[3]);
    n0 *= 511.0f; n1 *= 511.0f; n2 *= 511.0f;

    // ---- stores: one lane-role each ----
    if (q == 0) __builtin_nontemporal_store(o0, &out[p]);  // sdf
    if (q == 1) {
        const size_t nb = (size_t)N * 33 + (size_t)p * 3;
        __builtin_nontemporal_store(n0, &out[nb + 0]);
        __builtin_nontemporal_store(n1, &out[nb + 1]);
        __builtin_nontemporal_store(n2, &out[nb + 2]);
    }
    if (q == 2) {
        const size_t rb = (size_t)N * 36 + (size_t)p * 3;
        __builtin_nontemporal_store((tanhf(o1) + 1.0f) * 0.5f, &out[rb + 0]);
        __builtin_nontemporal_store((tanhf(o2) + 1.0f) * 0.5f, &out[rb + 1]);
        __builtin_nontemporal_store((tanhf(o3) + 1.0f) * 0.5f, &out[rb + 2]);
    }
#undef LD4
#undef GET
}

extern "C" void kernel_launch(void* const* d_in, const int* in_sizes, int n_in,
                              void* d_out, int out_size, void* d_ws, size_t ws_size,
                              hipStream_t stream) {
    const float* x      = (const float*)d_in[0];
    const float* planes = (const float*)d_in[1];
    const float* W1     = (const float*)d_in[2];
    const float* b1     = (const float*)d_in[3];
    const float* W2     = (const float*)d_in[4];
    const float* b2     = (const float*)d_in[5];
    float* out = (float*)d_out;
    const int N = in_sizes[0] / 3;

    // workspace layout: hist[NBINS] | cursor[NBINS] | order[N]  (u32 each)
    const size_t needed = (size_t)(2 * NBINS + N) * sizeof(unsigned);
    unsigned* order = nullptr;
    if (d_ws && ws_size >= needed) {
        unsigned* hist   = (unsigned*)d_ws;
        unsigned* cursor = hist + NBINS;
        order            = cursor + NBINS;
        zero_hist<<<NBINS / 256, 256, 0, stream>>>(hist);
        hist_pass<<<2048, 256, 0, stream>>>(x, hist, N);
        scan_pass<<<1, 256, 0, stream>>>(hist, cursor);
        scatter_pass<<<2048, 256, 0, stream>>>(x, cursor, order, N);
    }

    const long long total = 4LL * N;
    const int blocks = (int)((total + 255) / 256);
    stylesdf_fused<<<blocks, 256, 0, stream>>>(x, planes, W1, b1, W2, b2, order, out, N);
}